// Round 3
// baseline (997.138 us; speedup 1.0000x reference)
//
#include <hip/hip_runtime.h>
#include <stdint.h>

// LocallyConnected2D: out[b,f,or,oc] = relu( sum_{c,kh,kw} x[b,c,2or+kh,2oc+kw]*W[f,c,2or+kh,2oc+kw] + bias )
// bias raw-reshape: bias_flat[f*OR*OC + or*OC + oc]
//
// B=32 C=32 H=128 W=128 F=64 OR=OC=64. Memory-bound: ideal 236 MB -> ~37 us floor.
// Block = (orr, 16-oc tile): w-footprint = 32 floats = 128 B line-aligned -> every
// HBM line consumed by exactly one block (no fetch split). Block covers ALL b, ALL f.
// Grid 256 blocks x 1024 threads = 1 block/CU, 16 waves.
// Async double-buffered K-loop: global_load_lds(16B) for chunk k+1 issued before
// compute(k); steady-state wait = vmcnt(3) -> HBM busy during compute.
// LDS layout [ci*2+kh][b|f][w] (w innermost = lane-contiguous for global_load_lds);
// W compute-reads broadcast (free), x reads are structural 8-phase b128.

#define CC  32
#define HH  128
#define WWD 128
#define FF  64
#define ORR 64
#define OCC 64
#define CB  2            // channels per chunk
#define NIT (CC / CB)    // 16
#define CSTRIDE (CB * HH * WWD)   // 32768 floats per chunk advance

#define XBUF 4096        // CB*2kh*32b*32w floats = 16 KB
#define WBUF 8192        // CB*2kh*64f*32w floats = 32 KB

__global__ __launch_bounds__(1024) void lc2d_kernel(
    const float* __restrict__ x, const float* __restrict__ wgt,
    const float* __restrict__ bias, float* __restrict__ out)
{
    __shared__ __align__(16) float Xs[2][XBUF];   // 32 KB
    __shared__ __align__(16) float Ws[2][WBUF];   // 64 KB  (96 KB total)

    const int tid = threadIdx.x;
    const int id  = blockIdx.x;
    // oct pairs (0,1) and (2,3) share 128-B output lines -> ids differ by 128
    // (same id%8 -> same XCD) so L2 merges their half-line writes.
    const int oct = ((id & 1) << 1) | (id >> 7);   // 0..3 -> oc0 = oct*16
    const int orr = (id >> 1) & 63;
    const int w0  = oct * 32;                       // 32 w-floats = 128 B aligned
    const int h0  = orr * 2;

    const int lane = tid & 63;
    const int wv   = tid >> 6;        // wave id 0..15
    const int chk  = lane & 7;        // 16-B chunk within a 128-B global row
    const int sub  = lane >> 3;       // sub-row within this wave's slot

    // ---- staging global pointers (chunk 0); each wave owns contiguous LDS slots.
    // x slot wv: rows r = wv*8+sub in [0,128): layout row r = (ci*2+kh)*32 + b
    int r  = wv * 8 + sub;
    const float* gx  = x   + (((((r & 31) * CC) + (r >> 6)) * HH) + h0 + ((r >> 5) & 1)) * WWD + w0 + chk * 4;
    // W slots wv and wv+16: rows in [0,256): row = (ci*2+kh)*64 + f
    int r0 = wv * 8 + sub;
    const float* gw0 = wgt + (((((r0 & 63) * CC) + (r0 >> 7)) * HH) + h0 + ((r0 >> 6) & 1)) * WWD + w0 + chk * 4;
    int r1 = (wv + 16) * 8 + sub;
    const float* gw1 = wgt + (((((r1 & 63) * CC) + (r1 >> 7)) * HH) + h0 + ((r1 >> 6) & 1)) * WWD + w0 + chk * 4;

    auto issue = [&](int p) {
        __builtin_amdgcn_global_load_lds(
            (const __attribute__((address_space(1))) void*)gx,
            (__attribute__((address_space(3))) void*)(&Xs[p][wv * 256]), 16, 0, 0);
        __builtin_amdgcn_global_load_lds(
            (const __attribute__((address_space(1))) void*)gw0,
            (__attribute__((address_space(3))) void*)(&Ws[p][wv * 256]), 16, 0, 0);
        __builtin_amdgcn_global_load_lds(
            (const __attribute__((address_space(1))) void*)gw1,
            (__attribute__((address_space(3))) void*)(&Ws[p][4096 + wv * 256]), 16, 0, 0);
        gx += CSTRIDE; gw0 += CSTRIDE; gw1 += CSTRIDE;
    };

    // prologue: chunks 0 and 1 in flight
    issue(0);
    issue(1);

    // ---- compute thread mapping: ocg = w 4-chunk (2 oc), bg -> 4 b, fg(=wave) -> 4 f
    const int ocg = tid & 7;
    const int bg  = (tid >> 3) & 7;
    const int fg  = wv;
    const int xoff = bg * 128 + ocg * 4;   // (bg*4)*32 + ocg*4
    const int woff = fg * 128 + ocg * 4;   // (fg*4)*32 + ocg*4

    float acc0[4][4], acc1[4][4];          // [i=b][q=f], oc even / oc odd
#pragma unroll
    for (int i = 0; i < 4; ++i)
#pragma unroll
        for (int q = 0; q < 4; ++q) { acc0[i][q] = 0.f; acc1[i][q] = 0.f; }

#pragma unroll 2
    for (int it = 0; it < NIT; ++it) {
        const int p = it & 1;
        // wait for chunk `it` (3 newer loads for chunk it+1 may remain in flight)
        if (it == NIT - 1) __builtin_amdgcn_s_waitcnt(0x0F70);  // vmcnt(0)
        else               __builtin_amdgcn_s_waitcnt(0x0F73);  // vmcnt(3)
        __syncthreads();

        const float* Xp = Xs[p];
        const float* Wp = Ws[p];
#pragma unroll
        for (int s = 0; s < 2 * CB; ++s) {        // s = ci*2 + kh
            const float4* xr = (const float4*)(Xp + s * 1024 + xoff);
            const float4* wr = (const float4*)(Wp + s * 2048 + woff);
            float4 xa[4], wa[4];
#pragma unroll
            for (int i = 0; i < 4; ++i) xa[i] = xr[i * 8];   // b = bg*4 + i
#pragma unroll
            for (int q = 0; q < 4; ++q) wa[q] = wr[q * 8];   // f = fg*4 + q
#pragma unroll
            for (int i = 0; i < 4; ++i)
#pragma unroll
                for (int q = 0; q < 4; ++q) {
                    acc0[i][q] = fmaf(xa[i].x, wa[q].x, acc0[i][q]);
                    acc0[i][q] = fmaf(xa[i].y, wa[q].y, acc0[i][q]);
                    acc1[i][q] = fmaf(xa[i].z, wa[q].z, acc1[i][q]);
                    acc1[i][q] = fmaf(xa[i].w, wa[q].w, acc1[i][q]);
                }
        }
        __syncthreads();                  // buf p free for chunk it+2
        if (it + 2 < NIT) issue(p);
    }

    // ---- epilogue: bias (raw reshape [F][OR][OC]) + relu, float2 per (b,f)
    const int oc0 = oct * 16 + ocg * 2;
#pragma unroll
    for (int q = 0; q < 4; ++q) {
        const int f = fg * 4 + q;
        const float2 bv = *(const float2*)(bias + f * (ORR * OCC) + orr * OCC + oc0);
#pragma unroll
        for (int i = 0; i < 4; ++i) {
            const int b = bg * 4 + i;
            float2 o;
            o.x = fmaxf(acc0[i][q] + bv.x, 0.f);
            o.y = fmaxf(acc1[i][q] + bv.y, 0.f);
            *(float2*)(out + (((b * FF + f) * ORR + orr) * OCC) + oc0) = o;
        }
    }
}

extern "C" void kernel_launch(void* const* d_in, const int* in_sizes, int n_in,
                              void* d_out, int out_size, void* d_ws, size_t ws_size,
                              hipStream_t stream) {
    (void)in_sizes; (void)n_in; (void)d_ws; (void)ws_size; (void)out_size;
    const float* x    = (const float*)d_in[0];
    const float* wgt  = (const float*)d_in[1];
    const float* bias = (const float*)d_in[2];
    float* out        = (float*)d_out;
    lc2d_kernel<<<dim3(256, 1, 1), dim3(1024, 1, 1), 0, stream>>>(x, wgt, bias, out);
}

// Round 4
// 289.355 us; speedup vs baseline: 3.4461x; 3.4461x over previous
//
#include <hip/hip_runtime.h>
#include <stdint.h>

// LocallyConnected2D: out[b,f,or,oc] = relu( sum_{c,kh,kw} x[b,c,2or+kh,2oc+kw]*W[f,c,2or+kh,2oc+kw] + bias )
// bias raw-reshape: bias_flat[f*OR*OC + or*OC + oc]
//
// B=32 C=32 H=128 W=128 F=64 OR=OC=64. Memory-bound: ideal 236 MB -> ~37 us floor.
// Block = (orr, 16-oc tile): w-footprint = 32 floats = 128 B line-aligned -> every
// HBM line consumed by exactly one block. Block covers ALL b, ALL f (inputs read once).
// Grid 256 blocks x 1024 threads = 1 block/CU (LDS-limited), 16 waves.
// Async double-buffered K-loop: global_load_lds(16B) for chunk k+1 in flight during
// compute(k); steady-state wait = vmcnt(3) -> HBM stays busy through compute.
// R4 fix vs R3: __launch_bounds__(1024,4) -> VGPR cap 128 (was 64 -> massive scratch
// spills, 1.7 GB WRITE_SIZE); outer-loop unroll pragma removed (pressure).

#define CC  32
#define HH  128
#define WWD 128
#define FF  64
#define ORR 64
#define OCC 64
#define CB  2            // channels per chunk
#define NIT (CC / CB)    // 16
#define CSTRIDE (CB * HH * WWD)   // 32768 floats per chunk advance

#define XBUF 4096        // CB*2kh*32b*32w floats = 16 KB
#define WBUF 8192        // CB*2kh*64f*32w floats = 32 KB

__global__ __launch_bounds__(1024, 4) void lc2d_kernel(
    const float* __restrict__ x, const float* __restrict__ wgt,
    const float* __restrict__ bias, float* __restrict__ out)
{
    __shared__ __align__(16) float Xs[2][XBUF];   // 32 KB
    __shared__ __align__(16) float Ws[2][WBUF];   // 64 KB  (96 KB total)

    const int tid = threadIdx.x;
    const int id  = blockIdx.x;
    // oct pairs sharing 128-B output lines get ids differing by 128 (same id%8 ->
    // same XCD) so L2 merges their half-line writes.
    const int oct = ((id & 1) << 1) | (id >> 7);   // 0..3 -> oc0 = oct*16
    const int orr = (id >> 1) & 63;
    const int w0  = oct * 32;                       // 32 w-floats = 128 B aligned
    const int h0  = orr * 2;

    const int lane = tid & 63;
    const int wv   = tid >> 6;        // wave id 0..15
    const int chk  = lane & 7;        // 16-B chunk within a 128-B global row
    const int sub  = lane >> 3;       // sub-row within this wave's slot

    // ---- staging global pointers (chunk 0); each wave owns contiguous LDS slots.
    // x slot wv: rows r = wv*8+sub in [0,128): LDS row r = (ci*2+kh)*32 + b
    int r  = wv * 8 + sub;
    const float* gx  = x   + (((((r & 31) * CC) + (r >> 6)) * HH) + h0 + ((r >> 5) & 1)) * WWD + w0 + chk * 4;
    // W slots wv and wv+16: rows in [0,256): LDS row = (ci*2+kh)*64 + f
    int r0 = wv * 8 + sub;
    const float* gw0 = wgt + (((((r0 & 63) * CC) + (r0 >> 7)) * HH) + h0 + ((r0 >> 6) & 1)) * WWD + w0 + chk * 4;
    int r1 = (wv + 16) * 8 + sub;
    const float* gw1 = wgt + (((((r1 & 63) * CC) + (r1 >> 7)) * HH) + h0 + ((r1 >> 6) & 1)) * WWD + w0 + chk * 4;

    auto issue = [&](int p) {
        __builtin_amdgcn_global_load_lds(
            (const __attribute__((address_space(1))) void*)gx,
            (__attribute__((address_space(3))) void*)(&Xs[p][wv * 256]), 16, 0, 0);
        __builtin_amdgcn_global_load_lds(
            (const __attribute__((address_space(1))) void*)gw0,
            (__attribute__((address_space(3))) void*)(&Ws[p][wv * 256]), 16, 0, 0);
        __builtin_amdgcn_global_load_lds(
            (const __attribute__((address_space(1))) void*)gw1,
            (__attribute__((address_space(3))) void*)(&Ws[p][4096 + wv * 256]), 16, 0, 0);
        gx += CSTRIDE; gw0 += CSTRIDE; gw1 += CSTRIDE;
    };

    // prologue: chunks 0 and 1 in flight
    issue(0);
    issue(1);

    // ---- compute thread mapping: ocg = w 4-chunk (2 oc), bg -> 4 b, fg(=wave) -> 4 f
    const int ocg = tid & 7;
    const int bg  = (tid >> 3) & 7;
    const int fg  = wv;
    const int xoff = bg * 128 + ocg * 4;   // (bg*4)*32 + ocg*4
    const int woff = fg * 128 + ocg * 4;   // (fg*4)*32 + ocg*4

    float acc0[4][4], acc1[4][4];          // [i=b][q=f], oc even / oc odd
#pragma unroll
    for (int i = 0; i < 4; ++i)
#pragma unroll
        for (int q = 0; q < 4; ++q) { acc0[i][q] = 0.f; acc1[i][q] = 0.f; }

    for (int it = 0; it < NIT; ++it) {
        const int p = it & 1;
        // wait for chunk `it` (3 newer loads for chunk it+1 may remain in flight)
        if (it == NIT - 1) __builtin_amdgcn_s_waitcnt(0x0F70);  // vmcnt(0)
        else               __builtin_amdgcn_s_waitcnt(0x0F73);  // vmcnt(3)
        __syncthreads();

        const float* Xp = Xs[p];
        const float* Wp = Ws[p];
#pragma unroll
        for (int s = 0; s < 2 * CB; ++s) {        // s = ci*2 + kh
            const float4* xr = (const float4*)(Xp + s * 1024 + xoff);
            const float4* wr = (const float4*)(Wp + s * 2048 + woff);
            float4 xa[4], wa[4];
#pragma unroll
            for (int i = 0; i < 4; ++i) xa[i] = xr[i * 8];   // b = bg*4 + i
#pragma unroll
            for (int q = 0; q < 4; ++q) wa[q] = wr[q * 8];   // f = fg*4 + q
#pragma unroll
            for (int i = 0; i < 4; ++i)
#pragma unroll
                for (int q = 0; q < 4; ++q) {
                    acc0[i][q] = fmaf(xa[i].x, wa[q].x, acc0[i][q]);
                    acc0[i][q] = fmaf(xa[i].y, wa[q].y, acc0[i][q]);
                    acc1[i][q] = fmaf(xa[i].z, wa[q].z, acc1[i][q]);
                    acc1[i][q] = fmaf(xa[i].w, wa[q].w, acc1[i][q]);
                }
        }
        __syncthreads();                  // buf p free for chunk it+2
        if (it + 2 < NIT) issue(p);
    }

    // ---- epilogue: bias (raw reshape [F][OR][OC]) + relu, float2 per (b,f)
    const int oc0 = oct * 16 + ocg * 2;
#pragma unroll
    for (int q = 0; q < 4; ++q) {
        const int f = fg * 4 + q;
        const float2 bv = *(const float2*)(bias + f * (ORR * OCC) + orr * OCC + oc0);
#pragma unroll
        for (int i = 0; i < 4; ++i) {
            const int b = bg * 4 + i;
            float2 o;
            o.x = fmaxf(acc0[i][q] + bv.x, 0.f);
            o.y = fmaxf(acc1[i][q] + bv.y, 0.f);
            *(float2*)(out + (((b * FF + f) * ORR + orr) * OCC) + oc0) = o;
        }
    }
}

extern "C" void kernel_launch(void* const* d_in, const int* in_sizes, int n_in,
                              void* d_out, int out_size, void* d_ws, size_t ws_size,
                              hipStream_t stream) {
    (void)in_sizes; (void)n_in; (void)d_ws; (void)ws_size; (void)out_size;
    const float* x    = (const float*)d_in[0];
    const float* wgt  = (const float*)d_in[1];
    const float* bias = (const float*)d_in[2];
    float* out        = (float*)d_out;
    lc2d_kernel<<<dim3(256, 1, 1), dim3(1024, 1, 1), 0, stream>>>(x, wgt, bias, out);
}